// Round 14
// baseline (328.873 us; speedup 1.0000x reference)
//
#include <hip/hip_runtime.h>

#define BATCH   1024
#define MAXLEN  200
#define KCAPS   8
#define INU     256
#define OUTU    256
#define NEGPAD  -65535.0f
#define HSTR    264   // padded LDS row stride (floats)

typedef _Float16 f16;
typedef _Float16 f16x8 __attribute__((ext_vector_type(8)));
typedef float    f32x4 __attribute__((ext_vector_type(4)));

// ---------------- prep: Bcur copy + packed-frag S and S^T (hi/lo f16) ------
__global__ void k_prep(const float* __restrict__ S, const float* __restrict__ Bm,
                       f16* __restrict__ Shi, f16* __restrict__ Slo,
                       f16* __restrict__ Thi, f16* __restrict__ Tlo,
                       float* __restrict__ Bcur) {
    int idx = blockIdx.x * 256 + threadIdx.x;    // 0 .. 65535
    if (idx < KCAPS * MAXLEN) Bcur[idx] = Bm[idx];
    int j    = idx & 7;
    int lane = (idx >> 3) & 63;
    int nf   = (idx >> 9) & 15;
    int ks   = idx >> 13;
    int k = ks * 32 + (lane >> 4) * 8 + j;
    int n = nf * 16 + (lane & 15);
    float vS = S[k * 256 + n];
    f16 hS = (f16)vS;
    Shi[idx] = hS;
    Slo[idx] = (f16)(vS - (float)hS);
    float vT = S[n * 256 + k];
    f16 hT = (f16)vT;
    Thi[idx] = hT;
    Tlo[idx] = (f16)(vT - (float)hT);
}

// phase-E fragment: delta rows (MF)*16+r15, 8 ks in two 4-ks bursts
#define EFRAG(MF, ACC) do {                                                          \
    const int l_  = (MF) * 16 + r15;                                                 \
    const int lc_ = (l_ < MAXLEN) ? l_ : (MAXLEN - 1);                               \
    const float* ap_ = lb + (size_t)lc_ * INU + q * 8;                               \
    _Pragma("unroll")                                                                \
    for (int half = 0; half < 2; half++) {                                           \
        f32x4 va[4], vb[4];                                                          \
        _Pragma("unroll")                                                            \
        for (int kk = 0; kk < 4; kk++) {                                             \
            va[kk] = *reinterpret_cast<const f32x4*>(ap_ + (half * 4 + kk) * 32);    \
            vb[kk] = *reinterpret_cast<const f32x4*>(ap_ + (half * 4 + kk) * 32 + 4);\
        }                                                                            \
        _Pragma("unroll")                                                            \
        for (int kk = 0; kk < 4; kk++) {                                             \
            const int ob_ = (half * 4 + kk) * 32 + q * 8;                            \
            f32x4 h0 = *reinterpret_cast<const f32x4*>(&GH[r15 * HSTR + ob_]);       \
            f32x4 h1 = *reinterpret_cast<const f32x4*>(&GH[r15 * HSTR + ob_ + 4]);   \
            f16x8 bh, bl, ah, al;                                                    \
            _Pragma("unroll")                                                        \
            for (int j = 0; j < 4; j++) { f16 t = (f16)h0[j]; bh[j] = t; bl[j] = (f16)(h0[j] - (float)t); } \
            _Pragma("unroll")                                                        \
            for (int j = 0; j < 4; j++) { f16 t = (f16)h1[j]; bh[4+j] = t; bl[4+j] = (f16)(h1[j] - (float)t); } \
            _Pragma("unroll")                                                        \
            for (int j = 0; j < 4; j++) { f16 t = (f16)va[kk][j]; ah[j] = t; al[j] = (f16)(va[kk][j] - (float)t); } \
            _Pragma("unroll")                                                        \
            for (int j = 0; j < 4; j++) { f16 t = (f16)vb[kk][j]; ah[4+j] = t; al[4+j] = (f16)(vb[kk][j] - (float)t); } \
            ACC = __builtin_amdgcn_mfma_f32_16x16x32_f16(ah, bh, ACC, 0, 0, 0);      \
            ACC = __builtin_amdgcn_mfma_f32_16x16x32_f16(al, bh, ACC, 0, 0, 0);      \
            ACC = __builtin_amdgcn_mfma_f32_16x16x32_f16(ah, bl, ACC, 0, 0, 0);      \
        }                                                                            \
    }                                                                                \
} while (0)

// ---------------- fused per-iteration kernel (256 thr, 4 waves) ------------
// A: softmax (half-wave per k).  B: G = W @ low, 4 wave-partials, reduce 4->2
// into GH rows 0-15.  C: MFMA on the 16-row A absorbs the final 2-way sum
// (hp = D[k] + shfl_xor(D,32)), squash in-register.  D: T = H @ S^T (MFMA).
// E: delta = low @ T^T (MFMA, burst loads).  LDS = 6.4 + 16.9 KB -> 6 blk/CU.
__global__ __launch_bounds__(256, 6) void k_G(const float* __restrict__ Bcur,
                                              const int*   __restrict__ seq_len,
                                              const float* __restrict__ low,
                                              const f16*   __restrict__ Shi,
                                              const f16*   __restrict__ Slo,
                                              const f16*   __restrict__ Thi,
                                              const f16*   __restrict__ Tlo,
                                              float*       __restrict__ partials,
                                              float*       __restrict__ out,
                                              int do_T) {
    __shared__ float Wl[KCAPS * MAXLEN];     // 6.4 KB
    __shared__ float GH[16 * HSTR];          // 16.9 KB: Gparts -> Hl -> Tl
    const int b   = blockIdx.x;
    const int tid = threadIdx.x;
    const int len = seq_len[b];

    for (int i = tid; i < KCAPS * MAXLEN; i += 256) Wl[i] = Bcur[i];
    for (int i = tid; i < 16 * HSTR; i += 256) GH[i] = 0.f;
    __syncthreads();

    // phase A: masked softmax, one half-wave (32 lanes) per k
    {
        const int k  = tid >> 5;
        const int ln = tid & 31;
        float m = -3.4e38f;
        for (int l = ln; l < MAXLEN; l += 32) {
            float v = (l < len) ? Wl[k * MAXLEN + l] : NEGPAD;
            m = fmaxf(m, v);
        }
        #pragma unroll
        for (int off = 16; off >= 1; off >>= 1) m = fmaxf(m, __shfl_xor(m, off));
        float ssum = 0.f;
        for (int l = ln; l < MAXLEN; l += 32) {
            float v = (l < len) ? Wl[k * MAXLEN + l] : NEGPAD;
            ssum += __expf(v - m);
        }
        #pragma unroll
        for (int off = 16; off >= 1; off >>= 1) ssum += __shfl_xor(ssum, off);
        float inv = 1.f / ssum;
        for (int l = ln; l < MAXLEN; l += 32) {
            float v = (l < len) ? Wl[k * MAXLEN + l] : NEGPAD;
            Wl[k * MAXLEN + l] = __expf(v - m) * inv;
        }
    }
    __syncthreads();

    const float* lb = low + (size_t)b * (MAXLEN * INU);
    const int wv = tid >> 6, lane = tid & 63;
    const int r15 = lane & 15, q = lane >> 4;

    // phase B: G[k,:] = sum_l W[k,l]*low[l,:].  Wave wv handles rows l≡wv
    // (mod 4); one f32x4/lane = a full 1KB row per wave-load; software-
    // pipelined (vnext issued before the 32 fmaf on vcur). Partials reduce
    // 4->2 into GH rows 0-7 (w0+w2) and 8-15 (w1+w3); phase C sums the rest.
    {
        const int lim = (len == 0) ? MAXLEN : len;   // W==0 for l>=len when len>0
        f32x4 g[KCAPS];
        #pragma unroll
        for (int k = 0; k < KCAPS; k++) g[k] = (f32x4){0.f, 0.f, 0.f, 0.f};
        int l = wv;
        if (l < lim) {
            f32x4 vcur = *reinterpret_cast<const f32x4*>(lb + l * INU + lane * 4);
            for (;;) {
                const int ln2 = l + 4;
                const bool more = (ln2 < lim);       // wave-uniform
                f32x4 vnext;
                if (more) vnext = *reinterpret_cast<const f32x4*>(lb + ln2 * INU + lane * 4);
                #pragma unroll
                for (int k = 0; k < KCAPS; k++) {
                    const float wa = Wl[k * MAXLEN + l];   // wave-uniform broadcast
                    g[k][0] = fmaf(wa, vcur[0], g[k][0]);
                    g[k][1] = fmaf(wa, vcur[1], g[k][1]);
                    g[k][2] = fmaf(wa, vcur[2], g[k][2]);
                    g[k][3] = fmaf(wa, vcur[3], g[k][3]);
                }
                if (!more) break;
                l = ln2;
                vcur = vnext;
            }
        }
        if (wv >= 2) {
            #pragma unroll
            for (int k = 0; k < KCAPS; k++)
                *reinterpret_cast<f32x4*>(&GH[((wv - 2) * 8 + k) * HSTR + lane * 4]) = g[k];
        }
        __syncthreads();
        if (wv < 2) {
            #pragma unroll
            for (int k = 0; k < KCAPS; k++) {
                float* p = &GH[(wv * 8 + k) * HSTR + lane * 4];
                f32x4 t = *reinterpret_cast<const f32x4*>(p);
                *reinterpret_cast<f32x4*>(p) = t + g[k];
            }
        }
    }
    __syncthreads();

    // phase C (MFMA): D = Gparts(16 rows) @ S; hp[k] = D[k] + D[k+8] via
    // shfl_xor(32). Wave wv covers nf = wv*4 .. wv*4+3.
    f32x4 aC[4];
    #pragma unroll
    for (int i = 0; i < 4; i++) aC[i] = (f32x4){0.f, 0.f, 0.f, 0.f};
    #pragma unroll
    for (int ks = 0; ks < 8; ks++) {
        const float* gp = &GH[r15 * HSTR + ks * 32 + q * 8];
        f32x4 a0 = *reinterpret_cast<const f32x4*>(gp);
        f32x4 a1 = *reinterpret_cast<const f32x4*>(gp + 4);
        f16x8 ah, al;
        #pragma unroll
        for (int j = 0; j < 4; j++) {
            f16 t = (f16)a0[j]; ah[j] = t; al[j] = (f16)(a0[j] - (float)t);
        }
        #pragma unroll
        for (int j = 0; j < 4; j++) {
            f16 t = (f16)a1[j]; ah[4 + j] = t; al[4 + j] = (f16)(a1[j] - (float)t);
        }
        #pragma unroll
        for (int i = 0; i < 4; i++) {
            const int nf = wv * 4 + i;
            f16x8 bh = *reinterpret_cast<const f16x8*>(Shi + (ks * 16 + nf) * 512 + lane * 8);
            f16x8 bl = *reinterpret_cast<const f16x8*>(Slo + (ks * 16 + nf) * 512 + lane * 8);
            aC[i] = __builtin_amdgcn_mfma_f32_16x16x32_f16(ah, bh, aC[i], 0, 0, 0);
            aC[i] = __builtin_amdgcn_mfma_f32_16x16x32_f16(al, bh, aC[i], 0, 0, 0);
            aC[i] = __builtin_amdgcn_mfma_f32_16x16x32_f16(ah, bl, aC[i], 0, 0, 0);
        }
    }
    // partial-sum + squash (n over k per o): valid at q<2
    float s[4];
    #pragma unroll
    for (int i = 0; i < 4; i++) {
        #pragma unroll
        for (int r = 0; r < 4; r++) aC[i][r] += __shfl_xor(aC[i][r], 32);
        float n = aC[i][0]*aC[i][0] + aC[i][1]*aC[i][1] + aC[i][2]*aC[i][2] + aC[i][3]*aC[i][3];
        n += __shfl_xor(n, 16);
        s[i] = n / (1.f + n) * (1.f / sqrtf(n + 1e-9f));
    }
    if (!do_T) {
        if (q < 2) {
            #pragma unroll
            for (int i = 0; i < 4; i++) {
                const int col = (wv * 4 + i) * 16 + r15;
                #pragma unroll
                for (int r = 0; r < 4; r++)
                    out[((size_t)b * KCAPS + q * 4 + r) * OUTU + col] = s[i] * aC[i][r];
            }
        }
        return;
    }
    __syncthreads();                       // all phase-C reads of GH done
    // GH becomes Hl: rows 0-7 = H, rows 8-15 = 0 (every lane writes its cell)
    #pragma unroll
    for (int i = 0; i < 4; i++) {
        const int col = (wv * 4 + i) * 16 + r15;
        #pragma unroll
        for (int r = 0; r < 4; r++)
            GH[(q * 4 + r) * HSTR + col] = (q < 2) ? s[i] * aC[i][r] : 0.f;
    }
    __syncthreads();

    // phase D (MFMA): T[k][e] = sum_o H[k][o]*S[e][o]
    f32x4 aD[4];
    #pragma unroll
    for (int i = 0; i < 4; i++) aD[i] = (f32x4){0.f, 0.f, 0.f, 0.f};
    #pragma unroll
    for (int ks = 0; ks < 8; ks++) {
        const float* hp = &GH[r15 * HSTR + ks * 32 + q * 8];
        f32x4 a0 = *reinterpret_cast<const f32x4*>(hp);
        f32x4 a1 = *reinterpret_cast<const f32x4*>(hp + 4);
        f16x8 ah, al;
        #pragma unroll
        for (int j = 0; j < 4; j++) {
            f16 t = (f16)a0[j]; ah[j] = t; al[j] = (f16)(a0[j] - (float)t);
        }
        #pragma unroll
        for (int j = 0; j < 4; j++) {
            f16 t = (f16)a1[j]; ah[4 + j] = t; al[4 + j] = (f16)(a1[j] - (float)t);
        }
        #pragma unroll
        for (int i = 0; i < 4; i++) {
            const int nf = wv * 4 + i;
            f16x8 bh = *reinterpret_cast<const f16x8*>(Thi + (ks * 16 + nf) * 512 + lane * 8);
            f16x8 bl = *reinterpret_cast<const f16x8*>(Tlo + (ks * 16 + nf) * 512 + lane * 8);
            aD[i] = __builtin_amdgcn_mfma_f32_16x16x32_f16(ah, bh, aD[i], 0, 0, 0);
            aD[i] = __builtin_amdgcn_mfma_f32_16x16x32_f16(al, bh, aD[i], 0, 0, 0);
            aD[i] = __builtin_amdgcn_mfma_f32_16x16x32_f16(ah, bl, aD[i], 0, 0, 0);
        }
    }
    __syncthreads();                       // all phase-D reads of GH done
    // GH becomes Tl: rows 0-7 = T, rows 8-15 = 0
    #pragma unroll
    for (int i = 0; i < 4; i++) {
        const int col = (wv * 4 + i) * 16 + r15;
        #pragma unroll
        for (int r = 0; r < 4; r++)
            GH[(q * 4 + r) * HSTR + col] = (q < 2) ? aD[i][r] : 0.f;
    }
    __syncthreads();

    // phase E (MFMA): delta_T[l][k] = sum_e low[l,e]*T[k,e]; 13 frags / 4 waves
    f32x4 accA = (f32x4){0.f, 0.f, 0.f, 0.f};
    f32x4 accB = (f32x4){0.f, 0.f, 0.f, 0.f};
    f32x4 accC = (f32x4){0.f, 0.f, 0.f, 0.f};
    f32x4 accD = (f32x4){0.f, 0.f, 0.f, 0.f};
    EFRAG(wv, accA);
    EFRAG(wv + 4, accB);
    EFRAG(wv + 8, accC);
    if (wv == 0) EFRAG(12, accD);

    if (r15 < KCAPS) {
        const int kcol = r15;
        {
            const int lbase = wv * 16 + q * 4;                 // <= 63
            #pragma unroll
            for (int r = 0; r < 4; r++)
                partials[(size_t)(kcol * MAXLEN + lbase + r) * BATCH + b] = accA[r];
        }
        {
            const int lbase = (wv + 4) * 16 + q * 4;           // <= 127
            #pragma unroll
            for (int r = 0; r < 4; r++)
                partials[(size_t)(kcol * MAXLEN + lbase + r) * BATCH + b] = accB[r];
        }
        {
            const int lbase = (wv + 8) * 16 + q * 4;           // <= 191
            #pragma unroll
            for (int r = 0; r < 4; r++)
                partials[(size_t)(kcol * MAXLEN + lbase + r) * BATCH + b] = accC[r];
        }
        if (wv == 0) {
            const int lbase = 192 + q * 4;                     // may exceed 199
            #pragma unroll
            for (int r = 0; r < 4; r++) {
                const int l = lbase + r;
                if (l < MAXLEN)
                    partials[(size_t)(kcol * MAXLEN + l) * BATCH + b] = accD[r];
            }
        }
    }
}

// ---------------- B update: Bcur[i] += sum_b partials[i][b] ----------------
__global__ __launch_bounds__(256) void k_update(const float* __restrict__ partials,
                                                float* __restrict__ Bcur) {
    __shared__ float red[256];
    const int i   = blockIdx.x;
    const int tid = threadIdx.x;
    float s = 0.f;
    #pragma unroll
    for (int j = 0; j < BATCH / 256; j++) s += partials[(size_t)i * BATCH + tid + j * 256];
    red[tid] = s;
    __syncthreads();
    for (int st = 128; st > 0; st >>= 1) {
        if (tid < st) red[tid] += red[tid + st];
        __syncthreads();
    }
    if (tid == 0) Bcur[i] += red[0];
}

extern "C" void kernel_launch(void* const* d_in, const int* in_sizes, int n_in,
                              void* d_out, int out_size, void* d_ws, size_t ws_size,
                              hipStream_t stream) {
    const float* low = (const float*)d_in[0];
    const float* S   = (const float*)d_in[1];
    const float* Bm  = (const float*)d_in[2];
    const int*   seq = (const int*)d_in[3];
    float* out = (float*)d_out;

    char* ws = (char*)d_ws;
    float* Bcur     = (float*)ws;                     // 6,400 B
    float* partials = (float*)(ws + 6400);            // 6,553,600 B
    f16*   Shi      = (f16*)(ws + 6560000);           // 131,072 B
    f16*   Slo      = (f16*)(ws + 6691072);           // 131,072 B
    f16*   Thi      = (f16*)(ws + 6822144);           // 131,072 B
    f16*   Tlo      = (f16*)(ws + 6953216);           // 131,072 B

    k_prep<<<256, 256, 0, stream>>>(S, Bm, Shi, Slo, Thi, Tlo, Bcur);
    for (int it = 0; it < 3; it++) {
        int last = (it == 2);
        k_G<<<BATCH, 256, 0, stream>>>(Bcur, seq, low, Shi, Slo, Thi, Tlo,
                                       partials, out, last ? 0 : 1);
        if (!last) k_update<<<KCAPS * MAXLEN, 256, 0, stream>>>(partials, Bcur);
    }
}

// Round 15
// 211.078 us; speedup vs baseline: 1.5581x; 1.5581x over previous
//
#include <hip/hip_runtime.h>

#define BATCH   1024
#define MAXLEN  200
#define KCAPS   8
#define INU     256
#define OUTU    256
#define NEGPAD  -65535.0f
#define HSTR    264   // padded LDS row stride (floats)

typedef _Float16 f16;
typedef _Float16 f16x8 __attribute__((ext_vector_type(8)));
typedef float    f32x4 __attribute__((ext_vector_type(4)));
typedef float    f32x2 __attribute__((ext_vector_type(2)));

// ---------------- prep: Bcur copy + packed-frag S and S^T (hi/lo f16) ------
__global__ void k_prep(const float* __restrict__ S, const float* __restrict__ Bm,
                       f16* __restrict__ Shi, f16* __restrict__ Slo,
                       f16* __restrict__ Thi, f16* __restrict__ Tlo,
                       float* __restrict__ Bcur) {
    int idx = blockIdx.x * 256 + threadIdx.x;    // 0 .. 65535
    if (idx < KCAPS * MAXLEN) Bcur[idx] = Bm[idx];
    int j    = idx & 7;
    int lane = (idx >> 3) & 63;
    int nf   = (idx >> 9) & 15;
    int ks   = idx >> 13;
    int k = ks * 32 + (lane >> 4) * 8 + j;
    int n = nf * 16 + (lane & 15);
    float vS = S[k * 256 + n];
    f16 hS = (f16)vS;
    Shi[idx] = hS;
    Slo[idx] = (f16)(vS - (float)hS);
    float vT = S[n * 256 + k];
    f16 hT = (f16)vT;
    Thi[idx] = hT;
    Tlo[idx] = (f16)(vT - (float)hT);
}

// phase-E fragment: delta rows MF*16+r15, all 8 ks, burst-loaded
#define EFRAG(MF, ACC) do {                                                          \
    const int l_  = (MF) * 16 + r15;                                                 \
    const int lc_ = (l_ < MAXLEN) ? l_ : (MAXLEN - 1);                               \
    const float* ap_ = lb + (size_t)lc_ * INU + q * 8;                               \
    f32x4 va[8], vb[8];                                                              \
    _Pragma("unroll")                                                                \
    for (int ks = 0; ks < 8; ks++) {                                                 \
        va[ks] = *reinterpret_cast<const f32x4*>(ap_ + ks * 32);                     \
        vb[ks] = *reinterpret_cast<const f32x4*>(ap_ + ks * 32 + 4);                 \
    }                                                                                \
    _Pragma("unroll")                                                                \
    for (int ks = 0; ks < 8; ks++) {                                                 \
        const int ob_ = ks * 32 + q * 8;                                             \
        f32x4 h0 = *reinterpret_cast<const f32x4*>(&GH[r15 * HSTR + ob_]);           \
        f32x4 h1 = *reinterpret_cast<const f32x4*>(&GH[r15 * HSTR + ob_ + 4]);       \
        f16x8 bh, bl, ah, al;                                                        \
        _Pragma("unroll")                                                            \
        for (int j = 0; j < 4; j++) { f16 t = (f16)h0[j]; bh[j] = t; bl[j] = (f16)(h0[j] - (float)t); } \
        _Pragma("unroll")                                                            \
        for (int j = 0; j < 4; j++) { f16 t = (f16)h1[j]; bh[4+j] = t; bl[4+j] = (f16)(h1[j] - (float)t); } \
        _Pragma("unroll")                                                            \
        for (int j = 0; j < 4; j++) { f16 t = (f16)va[ks][j]; ah[j] = t; al[j] = (f16)(va[ks][j] - (float)t); } \
        _Pragma("unroll")                                                            \
        for (int j = 0; j < 4; j++) { f16 t = (f16)vb[ks][j]; ah[4+j] = t; al[4+j] = (f16)(vb[ks][j] - (float)t); } \
        ACC = __builtin_amdgcn_mfma_f32_16x16x32_f16(ah, bh, ACC, 0, 0, 0);          \
        ACC = __builtin_amdgcn_mfma_f32_16x16x32_f16(al, bh, ACC, 0, 0, 0);          \
        ACC = __builtin_amdgcn_mfma_f32_16x16x32_f16(ah, bl, ACC, 0, 0, 0);          \
    }                                                                                \
} while (0)

// ---------------- fused per-iteration kernel --------------------------------
__global__ __launch_bounds__(512, 4) void k_G(const float* __restrict__ Bcur,
                                              const int*   __restrict__ seq_len,
                                              const float* __restrict__ low,
                                              const f16*   __restrict__ Shi,
                                              const f16*   __restrict__ Slo,
                                              const f16*   __restrict__ Thi,
                                              const f16*   __restrict__ Tlo,
                                              float*       __restrict__ partials,
                                              float*       __restrict__ out,
                                              int do_T) {
    __shared__ float Wl[KCAPS * MAXLEN];     // 6.4 KB
    __shared__ float GH[16 * HSTR];          // 16.9 KB: Gl -> Hl -> Tl (rows 8..15 stay 0)
    __shared__ float Sl2[2 * KCAPS * 256];   // 16 KB reduce slab (2 regions)
    const int b   = blockIdx.x;
    const int tid = threadIdx.x;
    const int len = seq_len[b];

    for (int i = tid; i < KCAPS * MAXLEN; i += 512) Wl[i] = Bcur[i];
    for (int i = tid; i < 16 * HSTR; i += 512) GH[i] = 0.f;
    __syncthreads();

    // phase A: masked softmax, one 64-lane wave per k
    {
        const int k  = tid >> 6;
        const int ln = tid & 63;
        float m = -3.4e38f;
        for (int l = ln; l < MAXLEN; l += 64) {
            float v = (l < len) ? Wl[k * MAXLEN + l] : NEGPAD;
            m = fmaxf(m, v);
        }
        #pragma unroll
        for (int off = 32; off >= 1; off >>= 1) m = fmaxf(m, __shfl_xor(m, off));
        float ssum = 0.f;
        for (int l = ln; l < MAXLEN; l += 64) {
            float v = (l < len) ? Wl[k * MAXLEN + l] : NEGPAD;
            ssum += __expf(v - m);
        }
        #pragma unroll
        for (int off = 32; off >= 1; off >>= 1) ssum += __shfl_xor(ssum, off);
        float inv = 1.f / ssum;
        for (int l = ln; l < MAXLEN; l += 64) {
            float v = (l < len) ? Wl[k * MAXLEN + l] : NEGPAD;
            Wl[k * MAXLEN + l] = __expf(v - m) * inv;
        }
    }
    __syncthreads();

    const float* lb = low + (size_t)b * (MAXLEN * INU);

    // phase B: G[k,c] = sum_l W[k,l]*low[l,c].  128 col-pairs x 4 row-groups,
    // float2 loads, wave-uniform W broadcast, 2-round reduce.
    {
        const int cp = tid & 127;            // col-pair
        const int rg = tid >> 7;             // row group 0..3 (wave-uniform)
        const int lim = (len == 0) ? MAXLEN : len;
        const float* cb = lb + cp * 2;
        f32x2 g[KCAPS];
        #pragma unroll
        for (int k = 0; k < KCAPS; k++) g[k] = (f32x2){0.f, 0.f};
        int l = rg;
        for (; l + 4 < lim; l += 8) {
            f32x2 va = *reinterpret_cast<const f32x2*>(cb + l * INU);
            f32x2 vb = *reinterpret_cast<const f32x2*>(cb + (l + 4) * INU);
            #pragma unroll
            for (int k = 0; k < KCAPS; k++) {
                float wa = Wl[k * MAXLEN + l];
                float wb = Wl[k * MAXLEN + l + 4];
                g[k][0] = fmaf(wa, va[0], g[k][0]);
                g[k][1] = fmaf(wa, va[1], g[k][1]);
                g[k][0] = fmaf(wb, vb[0], g[k][0]);
                g[k][1] = fmaf(wb, vb[1], g[k][1]);
            }
        }
        if (l < lim) {
            f32x2 va = *reinterpret_cast<const f32x2*>(cb + l * INU);
            #pragma unroll
            for (int k = 0; k < KCAPS; k++) {
                float wa = Wl[k * MAXLEN + l];
                g[k][0] = fmaf(wa, va[0], g[k][0]);
                g[k][1] = fmaf(wa, va[1], g[k][1]);
            }
        }
        // reduce 4 groups -> GH rows 0..7
        if (rg >= 2) {
            #pragma unroll
            for (int k = 0; k < KCAPS; k++)
                *reinterpret_cast<f32x2*>(&Sl2[((rg - 2) * KCAPS + k) * 256 + cp * 2]) = g[k];
        }
        __syncthreads();
        if (rg == 1) {
            #pragma unroll
            for (int k = 0; k < KCAPS; k++) {
                f32x2 t = *reinterpret_cast<f32x2*>(&Sl2[(KCAPS + k) * 256 + cp * 2]);
                g[k][0] += t[0]; g[k][1] += t[1];
                *reinterpret_cast<f32x2*>(&Sl2[(KCAPS + k) * 256 + cp * 2]) = g[k];
            }
        } else if (rg == 0) {
            #pragma unroll
            for (int k = 0; k < KCAPS; k++) {
                f32x2 t = *reinterpret_cast<f32x2*>(&Sl2[k * 256 + cp * 2]);
                g[k][0] += t[0]; g[k][1] += t[1];
            }
        }
        __syncthreads();
        if (rg == 0) {
            #pragma unroll
            for (int k = 0; k < KCAPS; k++) {
                f32x2 t = *reinterpret_cast<f32x2*>(&Sl2[(KCAPS + k) * 256 + cp * 2]);
                GH[k * HSTR + cp * 2]     = g[k][0] + t[0];
                GH[k * HSTR + cp * 2 + 1] = g[k][1] + t[1];
            }
        }
    }
    __syncthreads();

    // phase C (MFMA): hp[k][o] = sum_e G[k][e]*S[e][o]; wave wv -> nf = 2wv, 2wv+1
    const int wv = tid >> 6, lane = tid & 63;
    const int r15 = lane & 15, q = lane >> 4;
    f32x4 aC[2];
    aC[0] = (f32x4){0.f, 0.f, 0.f, 0.f};
    aC[1] = (f32x4){0.f, 0.f, 0.f, 0.f};
    #pragma unroll
    for (int ks = 0; ks < 8; ks++) {
        const float* gp = &GH[r15 * HSTR + ks * 32 + q * 8];
        f32x4 a0 = *reinterpret_cast<const f32x4*>(gp);
        f32x4 a1 = *reinterpret_cast<const f32x4*>(gp + 4);
        f16x8 ah, al;
        #pragma unroll
        for (int j = 0; j < 4; j++) {
            f16 t = (f16)a0[j]; ah[j] = t; al[j] = (f16)(a0[j] - (float)t);
        }
        #pragma unroll
        for (int j = 0; j < 4; j++) {
            f16 t = (f16)a1[j]; ah[4 + j] = t; al[4 + j] = (f16)(a1[j] - (float)t);
        }
        #pragma unroll
        for (int i = 0; i < 2; i++) {
            const int nf = wv * 2 + i;
            f16x8 bh = *reinterpret_cast<const f16x8*>(Shi + (ks * 16 + nf) * 512 + lane * 8);
            f16x8 bl = *reinterpret_cast<const f16x8*>(Slo + (ks * 16 + nf) * 512 + lane * 8);
            aC[i] = __builtin_amdgcn_mfma_f32_16x16x32_f16(ah, bh, aC[i], 0, 0, 0);
            aC[i] = __builtin_amdgcn_mfma_f32_16x16x32_f16(al, bh, aC[i], 0, 0, 0);
            aC[i] = __builtin_amdgcn_mfma_f32_16x16x32_f16(ah, bl, aC[i], 0, 0, 0);
        }
    }
    // squash: thread holds hp[k=q*4+r][o=(2wv+i)*16+r15]; k<8 lives in q=0,1
    float s0, s1;
    {
        float n0 = aC[0][0]*aC[0][0] + aC[0][1]*aC[0][1] + aC[0][2]*aC[0][2] + aC[0][3]*aC[0][3];
        float n1 = aC[1][0]*aC[1][0] + aC[1][1]*aC[1][1] + aC[1][2]*aC[1][2] + aC[1][3]*aC[1][3];
        n0 += __shfl_xor(n0, 16);
        n1 += __shfl_xor(n1, 16);
        s0 = n0 / (1.f + n0) * (1.f / sqrtf(n0 + 1e-9f));
        s1 = n1 / (1.f + n1) * (1.f / sqrtf(n1 + 1e-9f));
    }
    if (!do_T) {
        if (q < 2) {
            #pragma unroll
            for (int r = 0; r < 4; r++) {
                out[((size_t)b * KCAPS + q * 4 + r) * OUTU + (wv * 2 + 0) * 16 + r15] = s0 * aC[0][r];
                out[((size_t)b * KCAPS + q * 4 + r) * OUTU + (wv * 2 + 1) * 16 + r15] = s1 * aC[1][r];
            }
        }
        return;
    }
    __syncthreads();                       // all phase-C reads of GH done
    if (q < 2) {                           // GH becomes Hl (rows 8..15 still 0)
        #pragma unroll
        for (int r = 0; r < 4; r++) {
            GH[(q * 4 + r) * HSTR + (wv * 2 + 0) * 16 + r15] = s0 * aC[0][r];
            GH[(q * 4 + r) * HSTR + (wv * 2 + 1) * 16 + r15] = s1 * aC[1][r];
        }
    }
    __syncthreads();

    // phase D (MFMA): T[k][e] = sum_o H[k][o]*S[e][o]
    f32x4 aD[2];
    aD[0] = (f32x4){0.f, 0.f, 0.f, 0.f};
    aD[1] = (f32x4){0.f, 0.f, 0.f, 0.f};
    #pragma unroll
    for (int ks = 0; ks < 8; ks++) {
        const float* hp = &GH[r15 * HSTR + ks * 32 + q * 8];
        f32x4 a0 = *reinterpret_cast<const f32x4*>(hp);
        f32x4 a1 = *reinterpret_cast<const f32x4*>(hp + 4);
        f16x8 ah, al;
        #pragma unroll
        for (int j = 0; j < 4; j++) {
            f16 t = (f16)a0[j]; ah[j] = t; al[j] = (f16)(a0[j] - (float)t);
        }
        #pragma unroll
        for (int j = 0; j < 4; j++) {
            f16 t = (f16)a1[j]; ah[4 + j] = t; al[4 + j] = (f16)(a1[j] - (float)t);
        }
        #pragma unroll
        for (int i = 0; i < 2; i++) {
            const int nf = wv * 2 + i;
            f16x8 bh = *reinterpret_cast<const f16x8*>(Thi + (ks * 16 + nf) * 512 + lane * 8);
            f16x8 bl = *reinterpret_cast<const f16x8*>(Tlo + (ks * 16 + nf) * 512 + lane * 8);
            aD[i] = __builtin_amdgcn_mfma_f32_16x16x32_f16(ah, bh, aD[i], 0, 0, 0);
            aD[i] = __builtin_amdgcn_mfma_f32_16x16x32_f16(al, bh, aD[i], 0, 0, 0);
            aD[i] = __builtin_amdgcn_mfma_f32_16x16x32_f16(ah, bl, aD[i], 0, 0, 0);
        }
    }
    __syncthreads();                       // all phase-D reads of GH done
    if (q < 2) {                           // GH becomes Tl (rows 8..15 still 0)
        #pragma unroll
        for (int r = 0; r < 4; r++) {
            GH[(q * 4 + r) * HSTR + (wv * 2 + 0) * 16 + r15] = aD[0][r];
            GH[(q * 4 + r) * HSTR + (wv * 2 + 1) * 16 + r15] = aD[1][r];
        }
    }
    __syncthreads();

    // phase E (MFMA): delta_T[l][k] = sum_e low[l,e]*T[k,e]; b-major partials
    // (contiguous 6.4KB per block -> coalesced writes, no cross-XCD line share)
    f32x4 accA = (f32x4){0.f, 0.f, 0.f, 0.f};
    f32x4 accB = (f32x4){0.f, 0.f, 0.f, 0.f};
    EFRAG(wv, accA);
    if (wv < 5) EFRAG(wv + 8, accB);

    if (r15 < KCAPS) {
        const int kcol = r15;
        float* pb = partials + (size_t)b * (KCAPS * MAXLEN);
        {   // frag A rows: l = wv*16 + q*4 + r  (max 127 < 200, no guard)
            const int lbase = wv * 16 + q * 4;
            #pragma unroll
            for (int r = 0; r < 4; r++)
                pb[(lbase + r) * KCAPS + kcol] = accA[r];
        }
        if (wv < 5) {   // frag B rows: l = (wv+8)*16 + q*4 + r (may exceed 199)
            const int lbase = (wv + 8) * 16 + q * 4;
            #pragma unroll
            for (int r = 0; r < 4; r++) {
                const int l = lbase + r;
                if (l < MAXLEN)
                    pb[l * KCAPS + kcol] = accB[r];
            }
        }
    }
}

// ---------------- B update: Bcur[k*200+l] += sum_b partials[b][l*8+k] ------
__global__ __launch_bounds__(256) void k_update(const float* __restrict__ partials,
                                                float* __restrict__ Bcur) {
    __shared__ float red[256];
    const int j   = blockIdx.x;            // 0..1599 ; l = j>>3, k = j&7
    const int tid = threadIdx.x;
    float s = 0.f;
    #pragma unroll
    for (int jj = 0; jj < BATCH / 256; jj++)
        s += partials[(size_t)(tid + jj * 256) * (KCAPS * MAXLEN) + j];
    red[tid] = s;
    __syncthreads();
    for (int st = 128; st > 0; st >>= 1) {
        if (tid < st) red[tid] += red[tid + st];
        __syncthreads();
    }
    if (tid == 0) Bcur[(j & 7) * MAXLEN + (j >> 3)] += red[0];
}

extern "C" void kernel_launch(void* const* d_in, const int* in_sizes, int n_in,
                              void* d_out, int out_size, void* d_ws, size_t ws_size,
                              hipStream_t stream) {
    const float* low = (const float*)d_in[0];
    const float* S   = (const float*)d_in[1];
    const float* Bm  = (const float*)d_in[2];
    const int*   seq = (const int*)d_in[3];
    float* out = (float*)d_out;

    char* ws = (char*)d_ws;
    float* Bcur     = (float*)ws;                     // 6,400 B
    float* partials = (float*)(ws + 6400);            // 6,553,600 B
    f16*   Shi      = (f16*)(ws + 6560000);           // 131,072 B
    f16*   Slo      = (f16*)(ws + 6691072);           // 131,072 B
    f16*   Thi      = (f16*)(ws + 6822144);           // 131,072 B
    f16*   Tlo      = (f16*)(ws + 6953216);           // 131,072 B

    k_prep<<<256, 256, 0, stream>>>(S, Bm, Shi, Slo, Thi, Tlo, Bcur);
    for (int it = 0; it < 3; it++) {
        int last = (it == 2);
        k_G<<<BATCH, 512, 0, stream>>>(Bcur, seq, low, Shi, Slo, Thi, Tlo,
                                       partials, out, last ? 0 : 1);
        if (!last) k_update<<<KCAPS * MAXLEN, 256, 0, stream>>>(partials, Bcur);
    }
}